// Round 6
// baseline (154.136 us; speedup 1.0000x reference)
//
#include <hip/hip_runtime.h>
#include <math.h>

#define N_EMBED 8192
#define DIM 32
#define NQ 32768              // 32*32*32 queries

#define QPB 128               // queries per block (4 waves x 32 rows)
#define NQG (NQ / QPB)        // 256 query groups
#define KSPL 8
#define KCHUNK (N_EMBED / KSPL)   // 1024 codes per block
#define TILE 128              // codes per LDS tile
#define NTILES (KCHUNK / TILE)    // 8
#define NPLANE 8              // p = s*4 + b8 ; s=0: h, s=1: m' = (x-h)*4096
#define LSTRIDE 130           // chunks per plane in LDS (+2 pad)

#define LOSS_OFF  1048576
#define ENT_OFF   1048577
#define IDX_OFF   1048578

typedef __attribute__((ext_vector_type(8))) _Float16 half8;
typedef __attribute__((ext_vector_type(16))) float floatx16;

// ---------------------------------------------------------------------------
// K0: per-code normalize + exact 2-way fp16 split + inv_norm table + zero side
// accumulators. One thread per code (32 blocks).
//   esplit chunk layout: plane p = s*4 + b8 (s=0: h=fp16(x); s=1:
//   m'=fp16((x-h)*4096)); chunk index = p*8192 + code; chunk = 8 halves = 16 B.
// ---------------------------------------------------------------------------
__global__ __launch_bounds__(256) void prep_kernel(const float* __restrict__ e,
                                                   half8* __restrict__ esplit,
                                                   float* __restrict__ inv_norm,
                                                   unsigned* __restrict__ usage,
                                                   float* __restrict__ loss_acc,
                                                   unsigned* __restrict__ done_ctr) {
    int k = blockIdx.x * 256 + threadIdx.x;    // 0..8191
    const float4* src = (const float4*)(e + k * DIM);
    float v[DIM];
    float ss = 0.f;
#pragma unroll
    for (int i = 0; i < 8; ++i) {
        float4 t = src[i];
        v[i*4+0] = t.x; v[i*4+1] = t.y; v[i*4+2] = t.z; v[i*4+3] = t.w;
        ss += t.x*t.x + t.y*t.y + t.z*t.z + t.w*t.w;
    }
    float inv = 1.f / fmaxf(sqrtf(ss), 1e-12f);
    inv_norm[k] = inv;
    usage[k] = 0u;
    if (k == 0) { loss_acc[0] = 0.f; done_ctr[0] = 0u; }

#pragma unroll
    for (int part = 0; part < 4; ++part) {
        half8 h8, m8;
#pragma unroll
        for (int j = 0; j < 8; ++j) {
            float xx = v[part * 8 + j] * inv;
            _Float16 h = (_Float16)xx;                          // RNE
            _Float16 m = (_Float16)((xx - (float)h) * 4096.0f); // exact residual, scaled
            h8[j] = h; m8[j] = m;
        }
        esplit[(0 * 4 + part) * N_EMBED + k] = h8;
        esplit[(1 * 4 + part) * N_EMBED + k] = m8;
    }
}

// ---------------------------------------------------------------------------
// K1: split-fp16 scorer on 32x32x16 MFMA (half the MFMA instrs of 16x16x32,
// faster pipe: 2495 vs 2176 TF). dot = hh + 2^-12(hm' + m'h), 3 terms x 2
// k-halves = 6 MFMAs per 32q x 32c tile. Wave owns 32 queries (rows); block =
// 4 waves = 128 queries; scans its 1024-code chunk double-buffered via LDS.
// Layouts (m74/m101 verified, dtype-independent):
//   A: row = lane&31, k = (lane>>5)*8 + j   (per k-half fragment)
//   B: col = lane&31, k = (lane>>5)*8 + j
//   C: col = lane&31, row = (reg&3) + 8*(reg>>2) + 4*(lane>>5)
// Top-1 per (query, chunk) -> keys8[kc*NQ+q], plain store (block owns slot).
// ---------------------------------------------------------------------------
__global__ __launch_bounds__(256, 3) void score_kernel(const float* __restrict__ z,
                                                       const half8* __restrict__ esplit,
                                                       unsigned long long* __restrict__ keys8) {
    __shared__ half8 lds[2][NPLANE * LSTRIDE];   // 33,280 B

    const int t = threadIdx.x;
    const int lane = t & 63;
    const int w = t >> 6;            // wave 0..3
    const int kh = lane >> 5;        // k-half selector (0/1)
    const int col = lane & 31;       // A-row / B-col / C-col
    const int qg = blockIdx.x & (NQG - 1);
    const int kc = blockIdx.x >> 8;          // 0..KSPL-1
    const int kbase = kc * KCHUNK;
    const int qbase = qg * QPB + w * 32;

    // ---- A fragments: 1 q-row per lane, on-the-fly normalize + fp16 split ----
    // lane holds k = kh*8+j (frag0) and 16+kh*8+j (frag1); lanes L, L+32 share
    // the query and jointly cover all 32 dims.
    half8 ah0, ah1, am0, am1;
    {
        int q = qbase + col;
        const float* zp = z + (q >> 10) * (DIM * 1024) + (q & 1023);
        float x[16];
        float ss = 0.f;
#pragma unroll
        for (int j = 0; j < 8; ++j) {
            x[j]     = zp[(kh * 8 + j) * 1024];
            x[8 + j] = zp[(16 + kh * 8 + j) * 1024];
        }
#pragma unroll
        for (int j = 0; j < 16; ++j) ss = fmaf(x[j], x[j], ss);
        ss += __shfl_xor(ss, 32, 64);    // combine the two k-halves of this query
        float inv = 1.f / fmaxf(sqrtf(ss), 1e-12f);
#pragma unroll
        for (int j = 0; j < 8; ++j) {
            float x0 = x[j] * inv;
            _Float16 h0 = (_Float16)x0;
            ah0[j] = h0; am0[j] = (_Float16)((x0 - (float)h0) * 4096.0f);
            float x1 = x[8 + j] * inv;
            _Float16 h1 = (_Float16)x1;
            ah1[j] = h1; am1[j] = (_Float16)((x1 - (float)h1) * 4096.0f);
        }
    }

    float best[16];
    int bk[16];
#pragma unroll
    for (int i = 0; i < 16; ++i) { best[i] = -2.0f; bk[i] = 0; }

    floatx16 z16;
#pragma unroll
    for (int i = 0; i < 16; ++i) z16[i] = 0.f;

    // ---- staging: 8 planes x 128 chunks = 1024 chunks / 256 threads = 4 ea ----
#pragma unroll
    for (int j = 0; j < 4; ++j) {
        int c = t + j * 256; int p = c >> 7, i = c & 127;
        lds[0][p * LSTRIDE + i] = esplit[p * N_EMBED + kbase + i];
    }
    __syncthreads();

    for (int kt = 0; kt < NTILES; ++kt) {
        half8 st[4];
        if (kt + 1 < NTILES) {
#pragma unroll
            for (int j = 0; j < 4; ++j) {
                int c = t + j * 256; int p = c >> 7, i = c & 127;
                st[j] = esplit[p * N_EMBED + kbase + (kt + 1) * TILE + i];
            }
        }
        const half8* __restrict__ buf = lds[kt & 1];
#pragma unroll
        for (int ct = 0; ct < TILE / 32; ++ct) {
            const half8* bp = buf + ct * 32 + col;
            half8 bh0 = bp[(0 + kh) * LSTRIDE];      // h, k 0..15
            half8 bh1 = bp[(2 + kh) * LSTRIDE];      // h, k 16..31
            half8 bm0 = bp[(4 + kh) * LSTRIDE];      // m', k 0..15
            half8 bm1 = bp[(6 + kh) * LSTRIDE];      // m', k 16..31

            floatx16 a0 = __builtin_amdgcn_mfma_f32_32x32x16_f16(ah0, bh0, z16, 0, 0, 0);
            floatx16 a1 = __builtin_amdgcn_mfma_f32_32x32x16_f16(ah0, bm0, z16, 0, 0, 0);
            a0 = __builtin_amdgcn_mfma_f32_32x32x16_f16(ah1, bh1, a0, 0, 0, 0);
            a1 = __builtin_amdgcn_mfma_f32_32x32x16_f16(am0, bh0, a1, 0, 0, 0);
            a1 = __builtin_amdgcn_mfma_f32_32x32x16_f16(ah1, bm1, a1, 0, 0, 0);
            a1 = __builtin_amdgcn_mfma_f32_32x32x16_f16(am1, bh1, a1, 0, 0, 0);

            const int kk = kbase + kt * TILE + ct * 32 + col;
#pragma unroll
            for (int r = 0; r < 16; ++r) {
                float d = fmaf(a1[r], 0x1p-12f, a0[r]);
                if (d > best[r]) { best[r] = d; bk[r] = kk; }
            }
        }
        __syncthreads();
        if (kt + 1 < NTILES) {
#pragma unroll
            for (int j = 0; j < 4; ++j) {
                int c = t + j * 256; int p = c >> 7, i = c & 127;
                lds[(kt + 1) & 1][p * LSTRIDE + i] = st[j];
            }
            __syncthreads();
        }
    }

    // ---- epilogue: pack (dot,k), reduce over the 32 cols, store per row ----
#pragma unroll
    for (int r = 0; r < 16; ++r) {
        unsigned ub = __float_as_uint(best[r]);
        ub = (ub & 0x80000000u) ? ~ub : (ub | 0x80000000u);
        unsigned long long key = ((unsigned long long)ub << 32) | (unsigned)(~bk[r]);
#pragma unroll
        for (int msk = 1; msk <= 16; msk <<= 1) {
            unsigned long long o = __shfl_xor(key, msk, 64);
            key = (o > key) ? o : key;
        }
        if (col == 0) {       // lanes 0 and 32: the two C row-halves
            int row = (r & 3) + 8 * (r >> 2) + 4 * kh;
            keys8[kc * NQ + qbase + row] = key;
        }
    }
}

// ---------------------------------------------------------------------------
// K2: finalize. Per query: max over the 8 per-chunk keys (coalesced 64 B; max
// = best dot, tie -> smallest idx; dots are bitwise-comparable across chunks
// since A/B frags don't depend on kc), then ONE row gather, histogram, z_q,
// straight-through out, loss. Last-done block computes entropy + loss scalars.
// (R5's exact rescore removed: 8 random row gathers/query were ~50 us; the
// 3-term split error ~1e-8 already decided same-chunk winners in R3/R5.)
// ---------------------------------------------------------------------------
__global__ __launch_bounds__(256) void finalize_kernel(const float* __restrict__ z,
                                                       const float* __restrict__ e,
                                                       const float* __restrict__ inv_norm,
                                                       const unsigned long long* __restrict__ keys8,
                                                       unsigned* __restrict__ usage,
                                                       float* __restrict__ loss_acc,
                                                       unsigned* __restrict__ done_ctr,
                                                       float* __restrict__ out) {
    int n = blockIdx.x * 256 + threadIdx.x;        // 0..NQ-1
    int b  = n >> 10;
    int hw = n & 1023;
    const float* zb = z + b * (DIM * 1024) + hw;

    float q[DIM];
    float ss = 0.f;
#pragma unroll
    for (int d = 0; d < DIM; ++d) {
        q[d] = zb[d * 1024];
        ss = fmaf(q[d], q[d], ss);
    }
    float inv = 1.f / fmaxf(sqrtf(ss), 1e-12f);
#pragma unroll
    for (int d = 0; d < DIM; ++d) q[d] *= inv;

    unsigned long long bestkey = 0ull;
#pragma unroll
    for (int c = 0; c < KSPL; ++c) {
        unsigned long long k8 = keys8[c * NQ + n];
        bestkey = (k8 > bestkey) ? k8 : bestkey;
    }
    int idx = (int)(~(unsigned)(bestkey & 0xFFFFFFFFull));

    atomicAdd(&usage[idx], 1u);

    // gather winner row, normalize via table, write straight-through + loss
    float inv2 = inv_norm[idx];
    const float4* er = (const float4*)(e + idx * DIM);
    float lsum = 0.f;
    float* outb = out + b * (DIM * 1024) + hw;
#pragma unroll
    for (int d8 = 0; d8 < 8; ++d8) {
        float4 t4 = er[d8];
        float w4[4] = {t4.x, t4.y, t4.z, t4.w};
#pragma unroll
        for (int j = 0; j < 4; ++j) {
            int d = d8 * 4 + j;
            float zq = w4[j] * inv2;
            float diff = zq - q[d];
            lsum = fmaf(diff, diff, lsum);
            outb[d * 1024] = q[d] + (zq - q[d]);   // faithful to zn + sg(z_q - zn)
        }
    }
    out[IDX_OFF + n] = (float)idx;

#pragma unroll
    for (int off = 32; off > 0; off >>= 1)
        lsum += __shfl_down(lsum, off, 64);
    if ((threadIdx.x & 63) == 0)
        atomicAdd(loss_acc, lsum);

    // ---- last-done block computes the scalars ----
    __shared__ unsigned lastflag;
    __syncthreads();
    if (threadIdx.x == 0) {
        __threadfence();
        unsigned prev = __hip_atomic_fetch_add(done_ctr, 1u, __ATOMIC_ACQ_REL,
                                               __HIP_MEMORY_SCOPE_AGENT);
        lastflag = (prev == gridDim.x - 1) ? 1u : 0u;
    }
    __syncthreads();
    if (lastflag) {
        __shared__ double sm[256];
        int t = threadIdx.x;
        double local = 0.0;
        const float denom = 32768.8192f;   // sum(usage)+K*eps; sum(usage)==NQ
        for (int k = t; k < N_EMBED; k += 256) {
            unsigned c = __hip_atomic_load(&usage[k], __ATOMIC_RELAXED,
                                           __HIP_MEMORY_SCOPE_AGENT);
            float p = ((float)c + 1e-4f) / denom;
            local += (double)(-(p * logf(p)));
        }
        sm[t] = local;
        __syncthreads();
        for (int s = 128; s > 0; s >>= 1) {
            if (t < s) sm[t] += sm[t + s];
            __syncthreads();
        }
        if (t == 0) {
            float la = __hip_atomic_load(loss_acc, __ATOMIC_RELAXED,
                                         __HIP_MEMORY_SCOPE_AGENT);
            out[LOSS_OFF] = (float)(1.25 * (double)la / 32768.0);  // (beta+1)*mean
            out[ENT_OFF]  = (float)sm[0];
        }
    }
}

// ---------------------------------------------------------------------------
extern "C" void kernel_launch(void* const* d_in, const int* in_sizes, int n_in,
                              void* d_out, int out_size, void* d_ws, size_t ws_size,
                              hipStream_t stream) {
    const float* z   = (const float*)d_in[0];   // (32, 32, 32, 32) bchw
    const float* emb = (const float*)d_in[1];   // (8192, 32)
    float* out = (float*)d_out;

    char* ws = (char*)d_ws;
    half8* esplit            = (half8*)ws;                                   // 1 MiB @ 0
    unsigned long long* keys8= (unsigned long long*)(ws + (1 << 20));        // 2 MiB @ 1 MiB
    float* inv_norm          = (float*)(ws + 3 * (1 << 20));                 // 32 KiB
    unsigned* usage          = (unsigned*)(ws + 3 * (1 << 20) + 32768);      // 32 KiB
    float* loss_acc          = (float*)(ws + 3 * (1 << 20) + 65536);
    unsigned* done_ctr       = (unsigned*)(ws + 3 * (1 << 20) + 65536 + 4);

    prep_kernel<<<N_EMBED / 256, 256, 0, stream>>>(emb, esplit, inv_norm, usage,
                                                   loss_acc, done_ctr);
    score_kernel<<<NQG * KSPL, 256, 0, stream>>>(z, esplit, keys8);
    finalize_kernel<<<NQ / 256, 256, 0, stream>>>(z, emb, inv_norm, keys8, usage,
                                                  loss_acc, done_ctr, out);
}

// Round 7
// 144.360 us; speedup vs baseline: 1.0677x; 1.0677x over previous
//
#include <hip/hip_runtime.h>
#include <math.h>

#define N_EMBED 8192
#define DIM 32
#define NQ 32768              // 32*32*32 queries

#define QPB 512               // queries per block (8 waves x 64)
#define NQG (NQ / QPB)        // 64 query groups
#define KSPL 16
#define KCHUNK (N_EMBED / KSPL)   // 512 codes per block
#define TILE 128              // codes per LDS tile
#define NTILES (KCHUNK / TILE)    // 4
#define NPLANE 8              // p = s*4 + part ; s=0: h, s=1: m' = (x-h)*4096
#define LSTRIDE 130           // chunks per plane in LDS (+2 pad: planes offset 8 banks)

#define LOSS_OFF  1048576
#define ENT_OFF   1048577
#define IDX_OFF   1048578

typedef __attribute__((ext_vector_type(8))) _Float16 half8;
typedef __attribute__((ext_vector_type(4))) float floatx4;

// ---------------------------------------------------------------------------
// K1: split-fp16 MFMA scorer, 16x16x32, 3 terms: dot = hh + 2^-12(hm' + m'h)
// (exact-split residual; error ~1e-8 rms << fp32 accum noise R1-R3 passed with).
// 512-thread blocks (8 waves -> 16 waves/CU resident; R5's 4-wave blocks sat
// at ~9.6 waves/CU and 38% of MFMA floor, R3's 8-wave got 55%).
// NO prep kernel: each block normalizes+splits its own 512-code chunk inline
// while staging raw e into LDS (dup work across the 64 blocks sharing a chunk
// is ~100 cyc/thread). Block 0 zeroes usage/loss/done (finalize is stream-
// ordered after ALL score blocks, so no race). One barrier per K-tile.
// Top-1 per (query, chunk) -> keys16[kc*NQ+q], plain store (block owns slot).
// ---------------------------------------------------------------------------
__global__ __launch_bounds__(512, 4) void score_kernel(const float* __restrict__ z,
                                                       const float* __restrict__ e,
                                                       unsigned long long* __restrict__ keys16,
                                                       unsigned* __restrict__ usage,
                                                       float* __restrict__ loss_acc,
                                                       unsigned* __restrict__ done_ctr) {
    __shared__ half8 lds[2][NPLANE * LSTRIDE];   // 33,280 B

    const int t = threadIdx.x;

    if (blockIdx.x == 0) {           // zero side accumulators for finalize
        for (int i = t; i < N_EMBED; i += 512) usage[i] = 0u;
        if (t == 0) { loss_acc[0] = 0.f; done_ctr[0] = 0u; }
    }

    const int lane = t & 63;
    const int w = t >> 6;            // wave 0..7
    const int quad = lane >> 4;      // k-group / C-row group
    const int lc = lane & 15;        // A-row / B-col / C-col
    const int qg = blockIdx.x & (NQG - 1);
    const int kc = blockIdx.x >> 6;          // 0..KSPL-1
    const int kbase = kc * KCHUNK;
    const int qbase = qg * QPB + w * 64;

    // ---- A fragments: 4 q-tiles of 16 rows, normalize + fp16 split ----
    half8 ah[4], am[4];
#pragma unroll
    for (int qt = 0; qt < 4; ++qt) {
        int q = qbase + qt * 16 + lc;
        const float* zp = z + (q >> 10) * (DIM * 1024) + (q & 1023);
        float x[8];
        float ss = 0.f;
#pragma unroll
        for (int j = 0; j < 8; ++j) {
            x[j] = zp[(quad * 8 + j) * 1024];
            ss = fmaf(x[j], x[j], ss);
        }
        ss += __shfl_xor(ss, 16, 64);   // combine the 4 quads holding this query
        ss += __shfl_xor(ss, 32, 64);
        float inv = 1.f / fmaxf(sqrtf(ss), 1e-12f);
#pragma unroll
        for (int j = 0; j < 8; ++j) {
            float xx = x[j] * inv;
            _Float16 h = (_Float16)xx;                           // RNE
            _Float16 m = (_Float16)((xx - (float)h) * 4096.0f);  // exact residual
            ah[qt][j] = h; am[qt][j] = m;
        }
    }

    // ---- stage: 128 codes/tile; 4 threads per code (one 8-dim part each),
    //      load raw e coalesced (32 B/thread), norm via 4-lane shfl, split,
    //      write h-plane (part) and m-plane (4+part) chunks to LDS.
    auto stage = [&](int bsel, int kt) {
        const int ci = t >> 2;           // code within tile, 0..127
        const int part = t & 3;          // 8-dim slice
        const int code = kbase + kt * TILE + ci;
        const float4* er = (const float4*)(e + code * DIM) + part * 2;
        float4 v0 = er[0], v1 = er[1];
        float x[8] = {v0.x, v0.y, v0.z, v0.w, v1.x, v1.y, v1.z, v1.w};
        float ss = 0.f;
#pragma unroll
        for (int j = 0; j < 8; ++j) ss = fmaf(x[j], x[j], ss);
        ss += __shfl_xor(ss, 1, 64);     // sum the 4 parts of this code
        ss += __shfl_xor(ss, 2, 64);
        float inv = 1.f / fmaxf(sqrtf(ss), 1e-12f);
        half8 h8, m8;
#pragma unroll
        for (int j = 0; j < 8; ++j) {
            float xx = x[j] * inv;
            _Float16 h = (_Float16)xx;
            _Float16 m = (_Float16)((xx - (float)h) * 4096.0f);
            h8[j] = h; m8[j] = m;
        }
        lds[bsel][part * LSTRIDE + ci] = h8;
        lds[bsel][(4 + part) * LSTRIDE + ci] = m8;
    };

    float best[16];
    int bk[16];
#pragma unroll
    for (int i = 0; i < 16; ++i) { best[i] = -2.0f; bk[i] = 0; }

    const floatx4 z4 = {0.f, 0.f, 0.f, 0.f};

    stage(0, 0);
    __syncthreads();

    for (int kt = 0; kt < NTILES; ++kt) {
        if (kt + 1 < NTILES) stage((kt + 1) & 1, kt + 1);   // buffer freed by last barrier

        const half8* __restrict__ buf = lds[kt & 1];
#pragma unroll 2
        for (int ct = 0; ct < TILE / 16; ++ct) {
            half8 bh = buf[(0 * 4 + quad) * LSTRIDE + ct * 16 + lc];
            half8 bm = buf[(1 * 4 + quad) * LSTRIDE + ct * 16 + lc];
            const int kk = kbase + kt * TILE + ct * 16 + lc;
#pragma unroll
            for (int qt = 0; qt < 4; ++qt) {
                floatx4 a0 = __builtin_amdgcn_mfma_f32_16x16x32_f16(ah[qt], bh, z4, 0, 0, 0);
                floatx4 a1 = __builtin_amdgcn_mfma_f32_16x16x32_f16(ah[qt], bm, z4, 0, 0, 0);
                a1 = __builtin_amdgcn_mfma_f32_16x16x32_f16(am[qt], bh, a1, 0, 0, 0);
#pragma unroll
                for (int r = 0; r < 4; ++r) {
                    float d = fmaf(a1[r], 0x1p-12f, a0[r]);
                    if (d > best[qt * 4 + r]) { best[qt * 4 + r] = d; bk[qt * 4 + r] = kk; }
                }
            }
        }
        __syncthreads();   // staged tile visible; computed buffer safe to overwrite
    }

    // ---- epilogue: pack (dot,k), reduce over 16 cols, plain store per row ----
#pragma unroll
    for (int i = 0; i < 16; ++i) {
        unsigned ub = __float_as_uint(best[i]);
        ub = (ub & 0x80000000u) ? ~ub : (ub | 0x80000000u);
        unsigned long long key = ((unsigned long long)ub << 32) | (unsigned)(~bk[i]);
#pragma unroll
        for (int msk = 1; msk <= 8; msk <<= 1) {
            unsigned long long o = __shfl_xor(key, msk, 64);
            key = (o > key) ? o : key;
        }
        if (lc == 0) {
            int qt = i >> 2, r = i & 3;
            int q = qbase + qt * 16 + quad * 4 + r;   // C row = quad*4 + reg
            keys16[kc * NQ + q] = key;                // block owns this slot
        }
    }
}

// ---------------------------------------------------------------------------
// K2: finalize. Per query: max over the 16 per-chunk keys (coalesced 128 B;
// max = best dot, tie -> smallest idx; dots bitwise-comparable across chunks
// since A/B frags are kc-independent), ONE row gather + local normalize,
// histogram, straight-through out, loss. Last-done block computes scalars.
// ---------------------------------------------------------------------------
__global__ __launch_bounds__(256) void finalize_kernel(const float* __restrict__ z,
                                                       const float* __restrict__ e,
                                                       const unsigned long long* __restrict__ keys16,
                                                       unsigned* __restrict__ usage,
                                                       float* __restrict__ loss_acc,
                                                       unsigned* __restrict__ done_ctr,
                                                       float* __restrict__ out) {
    int n = blockIdx.x * 256 + threadIdx.x;        // 0..NQ-1
    int b  = n >> 10;
    int hw = n & 1023;
    const float* zb = z + b * (DIM * 1024) + hw;

    float q[DIM];
    float ss = 0.f;
#pragma unroll
    for (int d = 0; d < DIM; ++d) {
        q[d] = zb[d * 1024];
        ss = fmaf(q[d], q[d], ss);
    }
    float inv = 1.f / fmaxf(sqrtf(ss), 1e-12f);
#pragma unroll
    for (int d = 0; d < DIM; ++d) q[d] *= inv;

    unsigned long long bestkey = 0ull;
#pragma unroll
    for (int c = 0; c < KSPL; ++c) {
        unsigned long long k16 = keys16[c * NQ + n];
        bestkey = (k16 > bestkey) ? k16 : bestkey;
    }
    int idx = (int)(~(unsigned)(bestkey & 0xFFFFFFFFull));

    atomicAdd(&usage[idx], 1u);

    // gather winner row, normalize locally, write straight-through + loss
    float wv[DIM];
    float ss2 = 0.f;
    const float4* er = (const float4*)(e + idx * DIM);
#pragma unroll
    for (int d8 = 0; d8 < 8; ++d8) {
        float4 t4 = er[d8];
        wv[d8*4+0] = t4.x; wv[d8*4+1] = t4.y; wv[d8*4+2] = t4.z; wv[d8*4+3] = t4.w;
        ss2 += t4.x*t4.x + t4.y*t4.y + t4.z*t4.z + t4.w*t4.w;
    }
    float inv2 = 1.f / fmaxf(sqrtf(ss2), 1e-12f);

    float lsum = 0.f;
    float* outb = out + b * (DIM * 1024) + hw;
#pragma unroll
    for (int d = 0; d < DIM; ++d) {
        float zq = wv[d] * inv2;
        float diff = zq - q[d];
        lsum = fmaf(diff, diff, lsum);
        outb[d * 1024] = q[d] + (zq - q[d]);   // faithful to zn + sg(z_q - zn)
    }
    out[IDX_OFF + n] = (float)idx;

#pragma unroll
    for (int off = 32; off > 0; off >>= 1)
        lsum += __shfl_down(lsum, off, 64);
    if ((threadIdx.x & 63) == 0)
        atomicAdd(loss_acc, lsum);

    // ---- last-done block computes the scalars ----
    __shared__ unsigned lastflag;
    __syncthreads();
    if (threadIdx.x == 0) {
        __threadfence();
        unsigned prev = __hip_atomic_fetch_add(done_ctr, 1u, __ATOMIC_ACQ_REL,
                                               __HIP_MEMORY_SCOPE_AGENT);
        lastflag = (prev == gridDim.x - 1) ? 1u : 0u;
    }
    __syncthreads();
    if (lastflag) {
        __shared__ double sm[256];
        int t = threadIdx.x;
        double local = 0.0;
        const float denom = 32768.8192f;   // sum(usage)+K*eps; sum(usage)==NQ
        for (int k = t; k < N_EMBED; k += 256) {
            unsigned c = __hip_atomic_load(&usage[k], __ATOMIC_RELAXED,
                                           __HIP_MEMORY_SCOPE_AGENT);
            float p = ((float)c + 1e-4f) / denom;
            local += (double)(-(p * logf(p)));
        }
        sm[t] = local;
        __syncthreads();
        for (int s = 128; s > 0; s >>= 1) {
            if (t < s) sm[t] += sm[t + s];
            __syncthreads();
        }
        if (t == 0) {
            float la = __hip_atomic_load(loss_acc, __ATOMIC_RELAXED,
                                         __HIP_MEMORY_SCOPE_AGENT);
            out[LOSS_OFF] = (float)(1.25 * (double)la / 32768.0);  // (beta+1)*mean
            out[ENT_OFF]  = (float)sm[0];
        }
    }
}

// ---------------------------------------------------------------------------
extern "C" void kernel_launch(void* const* d_in, const int* in_sizes, int n_in,
                              void* d_out, int out_size, void* d_ws, size_t ws_size,
                              hipStream_t stream) {
    const float* z   = (const float*)d_in[0];   // (32, 32, 32, 32) bchw
    const float* emb = (const float*)d_in[1];   // (8192, 32)
    float* out = (float*)d_out;

    char* ws = (char*)d_ws;
    unsigned long long* keys16 = (unsigned long long*)ws;                    // 4 MiB @ 0
    unsigned* usage            = (unsigned*)(ws + (4 << 20));                // 32 KiB
    float* loss_acc            = (float*)(ws + (4 << 20) + 32768);
    unsigned* done_ctr         = (unsigned*)(ws + (4 << 20) + 32768 + 4);

    score_kernel<<<NQG * KSPL, 512, 0, stream>>>(z, emb, keys16, usage,
                                                 loss_acc, done_ctr);
    finalize_kernel<<<NQ / 256, 256, 0, stream>>>(z, emb, keys16, usage,
                                                  loss_acc, done_ctr, out);
}